// Round 7
// baseline (39.692 us; speedup 1.0000x reference)
//
#include <hip/hip_runtime.h>

#define BB 8
#define NN 4096
#define THREADS 256
#define NSPLIT 64
#define CHUNK (NN / NSPLIT)     // 64 DB points per block
#define QPT 16                  // queries per thread -> 256*16 = 4096 = all queries of one (dir,b)
#define NQ (BB * NN)            // 32768 queries per direction
#define NQ_TOTAL (2 * NQ)       // 65536

// bid = dir*512 + b*64 + c ; dir0: db=a1,q=a2 (dist1), dir1: db=a2,q=a1
__global__ __launch_bounds__(THREADS) void chamfer_min_kernel(
    const float* __restrict__ a1, const float* __restrict__ a2,
    float* __restrict__ minpart)
{
    __shared__ float4 sdb[CHUNK];

    const int tid = threadIdx.x;
    const int bid = blockIdx.x;
    const int c   = bid & (NSPLIT - 1);
    const int b   = (bid >> 6) & 7;
    const int dir = bid >> 9;

    const float* dbg = (dir == 0 ? a1 : a2) + (size_t)b * NN * 3;
    const float* qg  = (dir == 0 ? a2 : a1) + (size_t)b * NN * 3;

    // stage CHUNK db points as (x, y, z, ||p||^2 / 2)
    if (tid < CHUNK) {
        const int i = c * CHUNK + tid;
        const float x = dbg[i * 3 + 0];
        const float y = dbg[i * 3 + 1];
        const float z = dbg[i * 3 + 2];
        sdb[tid] = make_float4(x, y, z, 0.5f * fmaf(x, x, fmaf(y, y, z * z)));
    }

    // 16 consecutive queries per thread (48 floats = 12 aligned float4 loads), negated
    float qx[QPT], qy[QPT], qz[QPT];
    {
        const float4* q4 = reinterpret_cast<const float4*>(qg + (size_t)tid * QPT * 3);
        #pragma unroll
        for (int v = 0; v < 4; ++v) {
            const float4 w0 = q4[v * 3 + 0];
            const float4 w1 = q4[v * 3 + 1];
            const float4 w2 = q4[v * 3 + 2];
            qx[v*4+0] = -w0.x; qy[v*4+0] = -w0.y; qz[v*4+0] = -w0.z;
            qx[v*4+1] = -w0.w; qy[v*4+1] = -w1.x; qz[v*4+1] = -w1.y;
            qx[v*4+2] = -w1.z; qy[v*4+2] = -w1.w; qz[v*4+2] = -w2.x;
            qx[v*4+3] = -w2.y; qy[v*4+3] = -w2.z; qz[v*4+3] = -w2.w;
        }
    }

    __syncthreads();

    float m[QPT];
    #pragma unroll
    for (int k = 0; k < QPT; ++k) m[k] = 3.4e38f;

    // t' = ||p||^2/2 - p.q ; per 2 points & query: 6 fma + 1 min3 (v_min3_f32)
    #pragma unroll 2
    for (int i = 0; i < CHUNK; i += 2) {
        const float4 p0 = sdb[i];
        const float4 p1 = sdb[i + 1];
        #pragma unroll
        for (int k = 0; k < QPT; ++k) {
            const float t0 = fmaf(p0.x, qx[k], fmaf(p0.y, qy[k], fmaf(p0.z, qz[k], p0.w)));
            const float t1 = fmaf(p1.x, qx[k], fmaf(p1.y, qy[k], fmaf(p1.z, qz[k], p1.w)));
            m[k] = fminf(fminf(t0, t1), m[k]);
        }
    }

    const size_t qglob = (size_t)dir * NQ + (size_t)b * NN + (size_t)tid * QPT;
    float4* dst = reinterpret_cast<float4*>(minpart + (size_t)c * NQ_TOTAL + qglob);
    #pragma unroll
    for (int v = 0; v < 4; ++v) {
        float4 o;
        o.x = m[v*4+0]; o.y = m[v*4+1]; o.z = m[v*4+2]; o.w = m[v*4+3];
        dst[v] = o;
    }
}

// combine the NSPLIT partial mins per query, add ||q||^2, block-sum
__global__ __launch_bounds__(THREADS) void decode_sum_kernel(
    const float* __restrict__ a1, const float* __restrict__ a2,
    const float* __restrict__ minpart, float* __restrict__ partials)
{
    __shared__ float red[THREADS];
    const int tid = threadIdx.x;
    const int bid = blockIdx.x;
    const int gq  = bid * THREADS + tid;
    const int dir = gq >> 15;
    const int b   = (gq >> 12) & 7;
    const int q   = gq & (NN - 1);

    float mn = 3.4e38f;
    #pragma unroll
    for (int cc = 0; cc < NSPLIT; ++cc)
        mn = fminf(mn, minpart[(size_t)cc * NQ_TOTAL + gq]);

    const float* qp = (dir == 0 ? a2 : a1) + ((size_t)b * NN + q) * 3;
    const float qx = qp[0], qy = qp[1], qz = qp[2];
    const float qn = fmaf(qx, qx, fmaf(qy, qy, qz * qz));
    const float d  = fmaf(2.0f, mn, qn);   // ||p-q||^2 = 2*t' + ||q||^2

    red[tid] = d;
    __syncthreads();
    #pragma unroll
    for (int s = THREADS / 2; s > 0; s >>= 1) {
        if (tid < s) red[tid] += red[tid + s];
        __syncthreads();
    }
    if (tid == 0) partials[bid] = red[0];
}

__global__ __launch_bounds__(256) void finalize_kernel(
    const float* __restrict__ partials, float* __restrict__ out)
{
    __shared__ float red[256];
    const int t = threadIdx.x;
    red[t] = partials[t];
    __syncthreads();
    #pragma unroll
    for (int s = 64; s > 0; s >>= 1) {
        if ((t & 127) < s) red[t] += red[t + s];
        __syncthreads();
    }
    if (t == 0) {
        const float inv = 1.0f / (float)(BB * NN);
        const float d1 = red[0]   * inv;   // dir0
        const float d2 = red[128] * inv;   // dir1
        out[0] = d1 + d2;
        out[1] = d1;
        out[2] = d2;
    }
}

extern "C" void kernel_launch(void* const* d_in, const int* in_sizes, int n_in,
                              void* d_out, int out_size, void* d_ws, size_t ws_size,
                              hipStream_t stream)
{
    const float* a1 = (const float*)d_in[0];
    const float* a2 = (const float*)d_in[1];
    float* out = (float*)d_out;

    float* minpart  = (float*)d_ws;   // 64*65536*4 = 16 MB
    float* partials = (float*)((char*)d_ws + (size_t)NSPLIT * NQ_TOTAL * sizeof(float));

    hipLaunchKernelGGL(chamfer_min_kernel, dim3(2 * BB * NSPLIT), dim3(THREADS), 0, stream,
                       a1, a2, minpart);
    hipLaunchKernelGGL(decode_sum_kernel, dim3(NQ_TOTAL / THREADS), dim3(THREADS), 0, stream,
                       a1, a2, minpart, partials);
    hipLaunchKernelGGL(finalize_kernel, dim3(1), dim3(256), 0, stream,
                       partials, out);
}

// Round 8
// 36.803 us; speedup vs baseline: 1.0785x; 1.0785x over previous
//
#include <hip/hip_runtime.h>

#define BB 8
#define NN 4096
#define THREADS 256
#define NSPLIT 16
#define CHUNK (NN / NSPLIT)     // 256 DB points per block
#define QPT 8                   // queries per thread
#define QPB (THREADS * QPT)     // 2048 queries per block
#define NQ (BB * NN)            // 32768 queries per direction
#define NQ_TOTAL (2 * NQ)       // 65536
#define DECODE_BLOCKS (NQ_TOTAL / THREADS)   // 256

// ws layout: [0, 4MB): minpart ; then acc[2] floats ; then counter uint
#define ACC_OFF ((size_t)NSPLIT * NQ_TOTAL)

// bid = dir*256 + b*32 + qb*16 + c ; dir0: db=a1,q=a2 (dist1), dir1: db=a2,q=a1
__global__ __launch_bounds__(THREADS) void chamfer_min_kernel(
    const float* __restrict__ a1, const float* __restrict__ a2,
    float* __restrict__ minpart)
{
    __shared__ float4 sdb[CHUNK];

    const int tid = threadIdx.x;
    const int bid = blockIdx.x;

    // zero the epilogue accumulators + counter (decode runs strictly after us)
    if (bid == 0 && tid < 3) {
        float* acc = minpart + ACC_OFF;
        acc[tid] = 0.0f;                       // acc[0], acc[1], acc[2](=counter as 0 bits)
    }

    const int c   = bid & (NSPLIT - 1);
    const int qb  = (bid >> 4) & 1;
    const int b   = (bid >> 5) & 7;
    const int dir = bid >> 8;

    const float* dbg = (dir == 0 ? a1 : a2) + (size_t)b * NN * 3;
    const float* qg  = (dir == 0 ? a2 : a1) + (size_t)b * NN * 3;

    // stage CHUNK db points as (x, y, z, ||p||^2 / 2)
    {
        const int i = c * CHUNK + tid;   // CHUNK == THREADS
        const float x = dbg[i * 3 + 0];
        const float y = dbg[i * 3 + 1];
        const float z = dbg[i * 3 + 2];
        sdb[tid] = make_float4(x, y, z, 0.5f * fmaf(x, x, fmaf(y, y, z * z)));
    }

    // 8 consecutive queries per thread (24 floats = 6 aligned float4 loads), negated
    float qx[QPT], qy[QPT], qz[QPT];
    {
        const float4* q4 = reinterpret_cast<const float4*>(
            qg + (size_t)(qb * QPB + tid * QPT) * 3);
        const float4 v0 = q4[0], v1 = q4[1], v2 = q4[2];
        const float4 v3 = q4[3], v4 = q4[4], v5 = q4[5];
        qx[0] = -v0.x; qy[0] = -v0.y; qz[0] = -v0.z;
        qx[1] = -v0.w; qy[1] = -v1.x; qz[1] = -v1.y;
        qx[2] = -v1.z; qy[2] = -v1.w; qz[2] = -v2.x;
        qx[3] = -v2.y; qy[3] = -v2.z; qz[3] = -v2.w;
        qx[4] = -v3.x; qy[4] = -v3.y; qz[4] = -v3.z;
        qx[5] = -v3.w; qy[5] = -v4.x; qz[5] = -v4.y;
        qx[6] = -v4.z; qy[6] = -v4.w; qz[6] = -v5.x;
        qx[7] = -v5.y; qy[7] = -v5.z; qz[7] = -v5.w;
    }

    __syncthreads();

    float m[QPT];
    #pragma unroll
    for (int k = 0; k < QPT; ++k) m[k] = 3.4e38f;

    // t' = ||p||^2/2 - p.q ; per 2 points & query: 6 fma + 1 v_min3_f32
    #pragma unroll 2
    for (int i = 0; i < CHUNK; i += 2) {
        const float4 p0 = sdb[i];
        const float4 p1 = sdb[i + 1];
        #pragma unroll
        for (int k = 0; k < QPT; ++k) {
            const float t0 = fmaf(p0.x, qx[k], fmaf(p0.y, qy[k], fmaf(p0.z, qz[k], p0.w)));
            const float t1 = fmaf(p1.x, qx[k], fmaf(p1.y, qy[k], fmaf(p1.z, qz[k], p1.w)));
            m[k] = fminf(fminf(t0, t1), m[k]);
        }
    }

    float4 o0, o1;
    o0.x = m[0]; o0.y = m[1]; o0.z = m[2]; o0.w = m[3];
    o1.x = m[4]; o1.y = m[5]; o1.z = m[6]; o1.w = m[7];

    const size_t qglob = (size_t)dir * NQ + (size_t)b * NN + (size_t)(qb * QPB + tid * QPT);
    float4* dst = reinterpret_cast<float4*>(minpart + (size_t)c * NQ_TOTAL + qglob);
    dst[0] = o0;
    dst[1] = o1;
}

// terminal kernel: combine slots, add ||q||^2, block-sum, atomic-accumulate,
// last block writes the 3 outputs. No separate finalize launch.
__global__ __launch_bounds__(THREADS) void decode_sum_kernel(
    const float* __restrict__ a1, const float* __restrict__ a2,
    float* __restrict__ minpart, float* __restrict__ out)
{
    __shared__ float red[THREADS];
    const int tid = threadIdx.x;
    const int bid = blockIdx.x;
    const int gq  = bid * THREADS + tid;
    const int dir = gq >> 15;
    const int b   = (gq >> 12) & 7;
    const int q   = gq & (NN - 1);

    float mn = 3.4e38f;
    #pragma unroll
    for (int cc = 0; cc < NSPLIT; ++cc)
        mn = fminf(mn, minpart[(size_t)cc * NQ_TOTAL + gq]);

    const float* qp = (dir == 0 ? a2 : a1) + ((size_t)b * NN + q) * 3;
    const float qx = qp[0], qy = qp[1], qz = qp[2];
    const float qn = fmaf(qx, qx, fmaf(qy, qy, qz * qz));
    const float d  = fmaf(2.0f, mn, qn);   // ||p-q||^2 = 2*t' + ||q||^2

    red[tid] = d;
    __syncthreads();
    #pragma unroll
    for (int s = THREADS / 2; s > 0; s >>= 1) {
        if (tid < s) red[tid] += red[tid + s];
        __syncthreads();
    }

    if (tid == 0) {
        float* acc = minpart + ACC_OFF;
        unsigned int* counter = (unsigned int*)(acc + 2);
        atomicAdd(&acc[dir], red[0]);
        __threadfence();
        const unsigned int old = atomicAdd(counter, 1u);
        if (old == DECODE_BLOCKS - 1) {
            // all block partials are in; coherent read via atomic RMW
            const float s1 = atomicAdd(&acc[0], 0.0f);
            const float s2 = atomicAdd(&acc[1], 0.0f);
            const float inv = 1.0f / (float)(BB * NN);
            const float d1 = s1 * inv;
            const float d2 = s2 * inv;
            out[0] = d1 + d2;
            out[1] = d1;
            out[2] = d2;
        }
    }
}

extern "C" void kernel_launch(void* const* d_in, const int* in_sizes, int n_in,
                              void* d_out, int out_size, void* d_ws, size_t ws_size,
                              hipStream_t stream)
{
    const float* a1 = (const float*)d_in[0];
    const float* a2 = (const float*)d_in[1];
    float* out = (float*)d_out;

    float* minpart = (float*)d_ws;   // 16*65536*4 = 4 MB, then acc[2]+counter

    hipLaunchKernelGGL(chamfer_min_kernel, dim3(2 * BB * 2 * NSPLIT), dim3(THREADS), 0, stream,
                       a1, a2, minpart);
    hipLaunchKernelGGL(decode_sum_kernel, dim3(DECODE_BLOCKS), dim3(THREADS), 0, stream,
                       a1, a2, minpart, out);
}